// Round 10
// baseline (178.379 us; speedup 1.0000x reference)
//
#include <hip/hip_runtime.h>
#include <hip/hip_bf16.h>
#include <math.h>

#define BB 8
#define NN 2048
#define TN 4096
#define DD 64

typedef __attribute__((ext_vector_type(8))) short short8;
typedef __attribute__((ext_vector_type(4))) float f32x4;
typedef __attribute__((ext_vector_type(4))) unsigned int u32x4;

union AF { unsigned int u[4]; short8 s8; };

__device__ __forceinline__ unsigned short f2bf(float f) {
    union { float f; unsigned int i; } v; v.f = f;
    unsigned int r = v.i + 0x7FFF + ((v.i >> 16) & 1);   // RNE
    return (unsigned short)(r >> 16);
}
__device__ __forceinline__ float bf2f(unsigned short u) {
    union { unsigned int i; float f; } v; v.i = ((unsigned int)u) << 16; return v.f;
}

// K1 v3: Wh = concat(ht,h) @ W (f32); s1 = Wh@a1, s2 = Wh@a2; exp tables.
// x-row reads are WAVE-UNIFORM -> row base forced uniform via readfirstlane
// so the 16 f32x4 loads/row compile to s_load (scalar cache, no LDS pipe,
// no vector VMEM). Old version broadcast x via LDS: 128 ds_read_b128/wave
// x 16 waves/CU x ~12cy ~= 10us of per-CU LDS-pipe serialization -- the k1
// bottleneck. W column stays in 64 VGPRs (v_fmac v,s,v: 1 SGPR operand,
// legal). FMA order unchanged.
__global__ __launch_bounds__(256, 4) void k1_wh(
                      const float* __restrict__ h,
                      const float* __restrict__ ht,
                      const float* __restrict__ W,
                      const float* __restrict__ a1,
                      const float* __restrict__ a2,
                      float* __restrict__ Wh,
                      float* __restrict__ E1p, float* __restrict__ E1n,
                      float* __restrict__ E2p, float* __restrict__ E2n,
                      float* __restrict__ E1i) {
    __shared__ float tr[4][8 * 68];                // per-wave transpose scratch
    __shared__ float ab[128];                      // a1 | a2
    int tid = threadIdx.x;
    int w = tid >> 6, l = tid & 63;
    float wreg[64];
    #pragma unroll
    for (int k = 0; k < 64; ++k) wreg[k] = W[k * 64 + l];
    if (tid < 128) ab[tid] = (tid < 64) ? a1[tid] : a2[tid - 64];
    __syncthreads();                               // ab visible to all waves
    int wu = __builtin_amdgcn_readfirstlane(w);    // uniform wave id
    int rowbase = (blockIdx.x * 4 + wu) * 8;       // 8 rows per wave, uniform
    int b = rowbase >> 12;
    int m0 = rowbase & (TN - 1);
    const float* srcw = (m0 < NN) ? (ht + ((size_t)b * NN + m0) * DD)
                                  : (h  + ((size_t)b * NN + (m0 - NN)) * DD);
    float acc8[8];
    #pragma unroll
    for (int r = 0; r < 8; ++r) {
        const f32x4* xr = reinterpret_cast<const f32x4*>(srcw + r * 64);
        float c0 = 0.f, c1 = 0.f, c2 = 0.f, c3 = 0.f;
        #pragma unroll
        for (int k = 0; k < 16; ++k) {
            f32x4 s = xr[k];                       // uniform -> s_load_dwordx4
            c0 += s[0] * wreg[k * 4 + 0];
            c1 += s[1] * wreg[k * 4 + 1];
            c2 += s[2] * wreg[k * 4 + 2];
            c3 += s[3] * wreg[k * 4 + 3];
        }
        acc8[r] = (c0 + c1) + (c2 + c3);
        Wh[((size_t)b * TN + m0 + r) * DD + l] = acc8[r];
    }
    // transpose through per-wave LDS (same-wave exchange: no barrier needed)
    #pragma unroll
    for (int r = 0; r < 8; ++r) tr[w][r * 68 + l] = acc8[r];
    int rr = l >> 3, cc = l & 7;
    f32x4 va  = *reinterpret_cast<const f32x4*>(&tr[w][rr * 68 + cc * 8]);
    f32x4 vb  = *reinterpret_cast<const f32x4*>(&tr[w][rr * 68 + cc * 8 + 4]);
    f32x4 a1a = *reinterpret_cast<const f32x4*>(&ab[cc * 8]);
    f32x4 a1b = *reinterpret_cast<const f32x4*>(&ab[cc * 8 + 4]);
    f32x4 a2a = *reinterpret_cast<const f32x4*>(&ab[64 + cc * 8]);
    f32x4 a2b = *reinterpret_cast<const f32x4*>(&ab[64 + cc * 8 + 4]);
    f32x4 s1v = va * a1a + vb * a1b;
    f32x4 s2v = va * a2a + vb * a2b;
    float p1 = (s1v[0] + s1v[1]) + (s1v[2] + s1v[3]);
    float p2 = (s2v[0] + s2v[1]) + (s2v[2] + s2v[3]);
    #pragma unroll
    for (int off = 1; off <= 4; off <<= 1) {
        p1 += __shfl_xor(p1, off, 64);
        p2 += __shfl_xor(p2, off, 64);
    }
    if (cc == 0) {                                 // 8 lanes, rows in parallel
        int mrow = m0 + rr;
        size_t o = (size_t)b * TN + mrow;
        float pp = __expf(p1), pn = __expf(0.2f * p1);
        E1p[o] = pp;
        E1n[o] = pn;
        int sp = (b < 4) ? b       : 8 + (b - 4);
        int sn = (b < 4) ? 4 + b   : 12 + (b - 4);
        E1i[(size_t)mrow * 16 + sp] = pp;
        E1i[(size_t)mrow * 16 + sn] = pn;
        E2p[o] = __expf(p2);
        E2n[o] = __expf(0.2f * p2);
    }
}

// K2: stream ONLY dense quadrants TL/BR. 32-row strips, grid (8,64,2)=1024
// blocks (4/CU). Software-pipelined it8 loop (16 loads in flight).
__global__ __launch_bounds__(256) void k2_mask_stats(
    const float* __restrict__ adj,
    const float* __restrict__ E1i,
    const float* __restrict__ E2p, const float* __restrict__ E2n,
    unsigned long long* __restrict__ qmask,
    float* __restrict__ Spart) {
    int tid = threadIdx.x;
    int w = tid >> 6, l = tid & 63;
    int half = blockIdx.z;
    int j = half * 2048 + blockIdx.x * 256 + tid;   // global column
    int i0 = half * 2048 + blockIdx.y * 32;         // global row base (32-strip)
    f32x4 e2p0, e2p1, e2n0, e2n1;
    #pragma unroll
    for (int b = 0; b < 4; ++b) {
        e2p0[b] = E2p[(size_t)b * TN + j];
        e2n0[b] = E2n[(size_t)b * TN + j];
        e2p1[b] = E2p[(size_t)(b + 4) * TN + j];
        e2n1[b] = E2n[(size_t)(b + 4) * TN + j];
    }
    f32x4 acc0 = {0.f, 0.f, 0.f, 0.f}, acc1 = {0.f, 0.f, 0.f, 0.f};
    const f32x4* e1 = reinterpret_cast<const f32x4*>(E1i + (size_t)i0 * 16);
    float avv[8];
    #pragma unroll
    for (int k = 0; k < 8; ++k)
        avv[k] = adj[(size_t)(i0 + k) * TN + j];
    for (int it8 = 0; it8 < 4; ++it8) {
        float avn[8];
        if (it8 < 3) {
            #pragma unroll
            for (int k = 0; k < 8; ++k)                   // prefetch next round
                avn[k] = adj[(size_t)(i0 + (it8 + 1) * 8 + k) * TN + j];
        }
        #pragma unroll
        for (int k = 0; k < 8; ++k) {
            int ii = it8 * 8 + k;
            unsigned long long bal = __ballot(avv[k] != 0.f);
            if (l == 0)
                qmask[(size_t)(i0 + ii) * 32 + blockIdx.x * 4 + w] = bal;
            f32x4 P0 = e1[ii * 4 + 0];                    // wave-uniform loads
            f32x4 N0 = e1[ii * 4 + 1];
            f32x4 P1 = e1[ii * 4 + 2];
            f32x4 N1 = e1[ii * 4 + 3];
            f32x4 v0 = __builtin_elementwise_max(P0 * e2p0, N0 * e2n0);
            f32x4 v1 = __builtin_elementwise_max(P1 * e2p1, N1 * e2n1);
            acc0 += v0 * avv[k];                          // av in {0,1}: exact mask
            acc1 += v1 * avv[k];
        }
        if (it8 < 3) {
            #pragma unroll
            for (int k = 0; k < 8; ++k) avv[k] = avn[k];
        }
    }
    #pragma unroll
    for (int b = 0; b < 4; ++b) {
        Spart[((size_t)blockIdx.y * 8 + b) * TN + j]     = acc0[b];
        Spart[((size_t)blockIdx.y * 8 + b + 4) * TN + j] = acc1[b];
    }
}

// K3: S = sum(64 strips) + identity term for j>=2048; then
// Whn_t[b][d][j] = Wh[b][j][d]/S[b][j] (bf16, transposed).
__global__ __launch_bounds__(256) void k3_whn(
    const float* __restrict__ Wh,
    const float* __restrict__ Spart,
    const float* __restrict__ E1p, const float* __restrict__ E1n,
    const float* __restrict__ E2p, const float* __restrict__ E2n,
    unsigned short* __restrict__ Wt) {
    __shared__ float tile[64][65];
    __shared__ float ps[4][64];
    __shared__ float rs[64];
    int b = blockIdx.y;
    int j0 = blockIdx.x * 64;
    int tid = threadIdx.x;
    int jj = tid & 63, part = tid >> 6;
    float s = 0.f;
    #pragma unroll
    for (int k = 0; k < 16; ++k) {
        int strip = part * 16 + k;
        s += Spart[((size_t)strip * 8 + b) * TN + j0 + jj];
    }
    ps[part][jj] = s;
    __syncthreads();
    if (tid < 64) {
        float tot = ps[0][tid] + ps[1][tid] + ps[2][tid] + ps[3][tid];
        int j = j0 + tid;
        if (j >= NN) {                 // identity column term (adj TR = I)
            int i = j - NN;
            tot += fmaxf(E1p[(size_t)b * TN + i] * E2p[(size_t)b * TN + j],
                         E1n[(size_t)b * TN + i] * E2n[(size_t)b * TN + j]);
        }
        rs[tid] = 1.0f / tot;
    }
    for (int e = tid; e < 4096; e += 256) {
        int jt = e >> 6, d = e & 63;
        tile[jt][d] = Wh[((size_t)b * TN + j0 + jt) * DD + d];
    }
    __syncthreads();
    for (int e = tid; e < 512; e += 256) {
        int d = e >> 3, jg = e & 7;
        union { unsigned short u[8]; short8 s8; } pk;
        #pragma unroll
        for (int k = 0; k < 8; ++k) {
            int jt = jg * 8 + k;
            pk.u[k] = f2bf(tile[jt][d] * rs[jt]);
        }
        *reinterpret_cast<short8*>(Wt + ((size_t)b * DD + d) * TN + j0 + jg * 8) = pk.s8;
    }
}

// K4 v3: each wave owns 32 i-rows (two 16-row groups acc0/acc1) so every
// B-fragment ds_read_b128 feeds TWO MFMAs. Block covers 128 i-rows; grid
// 1024 (4 blocks/CU). hpq layout unchanged (grp=it*8+w*2+gsel).
__global__ __launch_bounds__(256, 4) void k4_pv(
    const unsigned int* __restrict__ qmask32,
    const float* __restrict__ E1p, const float* __restrict__ E1n,
    const float* __restrict__ E2p, const float* __restrict__ E2n,
    const unsigned short* __restrict__ Wt,
    unsigned short* __restrict__ hpq) {
    __shared__ unsigned short wt_s[64 * 140];
    int bx = blockIdx.x;
    int b  = bx & 7;                 // XCD round-robin
    int js = (bx >> 3) & 3;
    int it = bx >> 5;                // i-tile index 0..31 (128 rows each)
    int i0 = it * 128;
    int half = (it >= 16);           // 0: i<2048 -> j in [0,2048); 1: [2048,4096)
    int tid = threadIdx.x;
    int w = tid >> 6, l = tid & 63;
    int m = l & 15, q = l >> 4;
    int irow0 = i0 + w * 32 + m;     // rows group 0
    int irow1 = irow0 + 16;          // rows group 1
    float e1p0 = E1p[(size_t)b * TN + irow0], e1n0 = E1n[(size_t)b * TN + irow0];
    float e1p1 = E1p[(size_t)b * TN + irow1], e1n1 = E1n[(size_t)b * TN + irow1];
    const float* e2pb = E2p + (size_t)b * TN;
    const float* e2nb = E2n + (size_t)b * TN;
    const unsigned short* wtb = Wt + (size_t)b * DD * TN;
    const unsigned int* mrow0 = qmask32 + (size_t)irow0 * 64;
    const unsigned int* mrow1 = qmask32 + (size_t)irow1 * 64;

    int r0 = tid >> 4, c0 = tid & 15;
    const int jbase = half * 2048 + js * 512;   // global j base
    const int jloc0 = js * 512;                 // local (in-half) bit base

    f32x4 acc0[4], acc1[4];
    #pragma unroll
    for (int dt = 0; dt < 4; ++dt) {
        acc0[dt] = (f32x4){0.f, 0.f, 0.f, 0.f};
        acc1[dt] = (f32x4){0.f, 0.f, 0.f, 0.f};
    }

    // prefetch tile jt=0 + masks jt=0
    short8 g[4];
    #pragma unroll
    for (int k = 0; k < 4; ++k)
        g[k] = *reinterpret_cast<const short8*>(
            wtb + (size_t)(r0 + 16 * k) * TN + jbase + c0 * 8);
    u32x4 m40 = *reinterpret_cast<const u32x4*>(mrow0 + (jloc0 >> 5));
    u32x4 m41 = *reinterpret_cast<const u32x4*>(mrow1 + (jloc0 >> 5));

    for (int jt = 0; jt < 4; ++jt) {
        int j0 = jbase + jt * 128;
        __syncthreads();                // prior reads done
        #pragma unroll
        for (int k = 0; k < 4; ++k)
            *reinterpret_cast<short8*>(&wt_s[(r0 + 16 * k) * 140 + c0 * 8]) = g[k];
        __syncthreads();                // tile visible
        u32x4 m40c = m40, m41c = m41;
        if (jt < 3) {                   // prefetch next tile DURING compute
            #pragma unroll
            for (int k = 0; k < 4; ++k)
                g[k] = *reinterpret_cast<const short8*>(
                    wtb + (size_t)(r0 + 16 * k) * TN + j0 + 128 + c0 * 8);
            m40 = *reinterpret_cast<const u32x4*>(
                mrow0 + ((jloc0 + (jt + 1) * 128) >> 5));
            m41 = *reinterpret_cast<const u32x4*>(
                mrow1 + ((jloc0 + (jt + 1) * 128) >> 5));
        }

        #pragma unroll
        for (int t = 0; t < 4; ++t) {
            int jb = j0 + t * 32 + q * 8;
            f32x4 p20 = *reinterpret_cast<const f32x4*>(e2pb + jb);
            f32x4 p21 = *reinterpret_cast<const f32x4*>(e2pb + jb + 4);
            f32x4 n20 = *reinterpret_cast<const f32x4*>(e2nb + jb);
            f32x4 n21 = *reinterpret_cast<const f32x4*>(e2nb + jb + 4);
            AF af0, af1;
            #pragma unroll
            for (int gsel = 0; gsel < 2; ++gsel) {
                float e1p_v = gsel ? e1p1 : e1p0;
                float e1n_v = gsel ? e1n1 : e1n0;
                unsigned int bytev = ((gsel ? m41c : m40c)[t] >> (q * 8)) & 0xFFu;
                f32x4 v0 = __builtin_elementwise_max(p20 * e1p_v, n20 * e1n_v);
                f32x4 v1 = __builtin_elementwise_max(p21 * e1p_v, n21 * e1n_v);
                union { f32x4 f; u32x4 u; } uv0, uv1;
                uv0.f = v0; uv1.f = v1;
                u32x4 mk0, mk1;
                #pragma unroll
                for (int c = 0; c < 4; ++c) {
                    mk0[c] = (unsigned int)((int)(bytev << (31 - c)) >> 31);
                    mk1[c] = (unsigned int)((int)(bytev << (27 - c)) >> 31);
                }
                uv0.u &= mk0; uv1.u &= mk1;
                __hip_bfloat162 hb0 = __float22bfloat162_rn(make_float2(uv0.f[0], uv0.f[1]));
                __hip_bfloat162 hb1 = __float22bfloat162_rn(make_float2(uv0.f[2], uv0.f[3]));
                __hip_bfloat162 hb2 = __float22bfloat162_rn(make_float2(uv1.f[0], uv1.f[1]));
                __hip_bfloat162 hb3 = __float22bfloat162_rn(make_float2(uv1.f[2], uv1.f[3]));
                AF& af = gsel ? af1 : af0;
                af.u[0] = *reinterpret_cast<unsigned int*>(&hb0);
                af.u[1] = *reinterpret_cast<unsigned int*>(&hb1);
                af.u[2] = *reinterpret_cast<unsigned int*>(&hb2);
                af.u[3] = *reinterpret_cast<unsigned int*>(&hb3);
            }
            #pragma unroll
            for (int dt = 0; dt < 4; ++dt) {
                short8 bf = *reinterpret_cast<const short8*>(
                    &wt_s[(dt * 16 + m) * 140 + t * 32 + q * 8]);   // 1 read, 2 MFMAs
                acc0[dt] = __builtin_amdgcn_mfma_f32_16x16x32_bf16(af0.s8, bf, acc0[dt], 0, 0, 0);
                acc1[dt] = __builtin_amdgcn_mfma_f32_16x16x32_bf16(af1.s8, bf, acc1[dt], 0, 0, 0);
            }
        }
    }

    // Diagonal identity term + epilogue per 16-row group.
    #pragma unroll
    for (int gsel = 0; gsel < 2; ++gsel) {
        f32x4* acc = gsel ? acc1 : acc0;
        int gbase = i0 + w * 32 + gsel * 16 + q * 4;
        if (half == 0 && js == 0) {
            #pragma unroll
            for (int r = 0; r < 4; ++r) {
                int gg = gbase + r;
                float ed = fmaxf(E1p[(size_t)b * TN + gg] * e2pb[gg + NN],
                                 E1n[(size_t)b * TN + gg] * e2nb[gg + NN]);
                #pragma unroll
                for (int dt = 0; dt < 4; ++dt) {
                    int d = dt * 16 + m;
                    acc[dt][r] += ed * bf2f(wtb[(size_t)d * TN + gg + NN]);
                }
            }
        }
        // lane-native bf16 pack; row-group index grp keeps k5 layout intact
        union { unsigned int u[8]; u32x4 v[2]; } pk;
        #pragma unroll
        for (int dt = 0; dt < 4; ++dt) {
            __hip_bfloat162 p0 = __float22bfloat162_rn(make_float2(acc[dt][0], acc[dt][1]));
            __hip_bfloat162 p1 = __float22bfloat162_rn(make_float2(acc[dt][2], acc[dt][3]));
            pk.u[dt * 2 + 0] = *reinterpret_cast<unsigned int*>(&p0);
            pk.u[dt * 2 + 1] = *reinterpret_cast<unsigned int*>(&p1);
        }
        int grp = it * 8 + w * 2 + gsel;           // absolute 16-row group 0..255
        unsigned short* hp = hpq +
            ((((size_t)js * 8 + b) * 256 + grp) * 64 + l) * 16;
        *reinterpret_cast<u32x4*>(hp)     = pk.v[0];
        *reinterpret_cast<u32x4*>(hp + 8) = pk.v[1];
    }
}

// K5: block = (b,it), wave geometry MATCHES k4's writes -> fully coalesced
// u32x4 reads. js-sum in f32, ELU, LDS transpose [64][68], vector f32
// stores with concat remap. 24 MB total traffic.
__global__ __launch_bounds__(256) void k5_epi(const unsigned short* __restrict__ hpq,
                                              float* __restrict__ out) {
    __shared__ float tile[64][68];
    int bx = blockIdx.x;                 // 0..511
    int b  = bx & 7;
    int it = bx >> 3;                    // 0..63
    int tid = threadIdx.x;
    int w = tid >> 6, l = tid & 63;
    int m = l & 15, q = l >> 4;
    const size_t JSTR = (size_t)8 * 64 * 4 * 64 * 16;   // ushorts per js slab
    size_t base = ((((size_t)b * 64 + it) * 4 + w) * 64 + l) * 16;
    float sum[16];
    #pragma unroll
    for (int k = 0; k < 16; ++k) sum[k] = 0.f;
    #pragma unroll
    for (int js = 0; js < 4; ++js) {
        const u32x4* p = reinterpret_cast<const u32x4*>(hpq + js * JSTR + base);
        u32x4 v0 = p[0], v1 = p[1];
        unsigned int uu[8];
        *reinterpret_cast<u32x4*>(&uu[0]) = v0;
        *reinterpret_cast<u32x4*>(&uu[4]) = v1;
        #pragma unroll
        for (int k = 0; k < 16; ++k) {
            int word = (k >> 2) * 2 + ((k >> 1) & 1);
            int hi = k & 1;
            sum[k] += bf2f((unsigned short)((uu[word] >> (hi * 16)) & 0xFFFFu));
        }
    }
    // ELU then scatter into LDS transpose tile: row=w*16+q*4+r, col=dt*16+m
    #pragma unroll
    for (int dt = 0; dt < 4; ++dt) {
        #pragma unroll
        for (int r = 0; r < 4; ++r) {
            float v = sum[dt * 4 + r];
            v = (v > 0.f) ? v : expm1f(v);
            tile[w * 16 + q * 4 + r][dt * 16 + m] = v;
        }
    }
    __syncthreads();
    int rl = tid >> 2, c0 = (tid & 3) * 16;
    int gg = it * 64 + rl;
    int half = (it >= 32);
    int n = gg - half * NN;
    float* orow = out + ((size_t)b * NN + n) * 128 + half * 64 + c0;
    #pragma unroll
    for (int c = 0; c < 4; ++c)
        *reinterpret_cast<f32x4*>(orow + c * 4) =
            *reinterpret_cast<const f32x4*>(&tile[rl][c0 + c * 4]);
}

extern "C" void kernel_launch(void* const* d_in, const int* in_sizes, int n_in,
                              void* d_out, int out_size, void* d_ws, size_t ws_size,
                              hipStream_t stream) {
    const float* h   = (const float*)d_in[0];
    const float* ht  = (const float*)d_in[1];
    const float* W   = (const float*)d_in[2];
    const float* a1  = (const float*)d_in[3];
    const float* a2  = (const float*)d_in[4];
    const float* adj = (const float*)d_in[5];
    float* out = (float*)d_out;

    char* ws = (char*)d_ws;
    float* Wh          = (float*)(ws);                       // 8 MB
    float* Spart       = (float*)(ws + (8 << 20));           // 8 MB (64 strips)
    unsigned short* Wt = (unsigned short*)(ws + (16 << 20)); // 4 MB
    float* E1p         = (float*)(ws + (20 << 20));
    float* E1n         = (float*)(ws + (20 << 20) + (128 << 10));
    float* E2p         = (float*)(ws + (20 << 20) + (256 << 10));
    float* E2n         = (float*)(ws + (20 << 20) + (384 << 10));
    unsigned long long* qmask = (unsigned long long*)(ws + (20 << 20) + (512 << 10)); // 1 MB
    float* E1i         = (float*)(ws + (20 << 20) + (512 << 10) + (2 << 20)); // 256 KB
    const unsigned int* qmask32 = (const unsigned int*)qmask;
    // 4 bf16 partial slabs (4 MB each, lane-native layout) overlay Wh+Spart
    unsigned short* hpq = (unsigned short*)ws;               // 16 MB total

    k1_wh<<<dim3(BB * TN / 32), dim3(256), 0, stream>>>(h, ht, W, a1, a2, Wh,
                                                        E1p, E1n, E2p, E2n, E1i);
    k2_mask_stats<<<dim3(8, 64, 2), dim3(256), 0, stream>>>(adj, E1i, E2p, E2n,
                                                            qmask, Spart);
    k3_whn<<<dim3(64, 8), dim3(256), 0, stream>>>(Wh, Spart, E1p, E1n, E2p, E2n, Wt);
    k4_pv<<<dim3(1024), dim3(256), 0, stream>>>(qmask32, E1p, E1n, E2p, E2n, Wt,
                                                hpq);
    k5_epi<<<dim3(512), dim3(256), 0, stream>>>(hpq, out);
}

// Round 11
// 171.187 us; speedup vs baseline: 1.0420x; 1.0420x over previous
//
#include <hip/hip_runtime.h>
#include <hip/hip_bf16.h>
#include <math.h>

#define BB 8
#define NN 2048
#define TN 4096
#define DD 64

typedef __attribute__((ext_vector_type(8))) short short8;
typedef __attribute__((ext_vector_type(4))) float f32x4;
typedef __attribute__((ext_vector_type(4))) unsigned int u32x4;

union AF { unsigned int u[4]; short8 s8; };

__device__ __forceinline__ unsigned short f2bf(float f) {
    union { float f; unsigned int i; } v; v.f = f;
    unsigned int r = v.i + 0x7FFF + ((v.i >> 16) & 1);   // RNE
    return (unsigned short)(r >> 16);
}
__device__ __forceinline__ float bf2f(unsigned short u) {
    union { unsigned int i; float f; } v; v.i = ((unsigned int)u) << 16; return v.f;
}

// K1 (reverted to R8 LDS-staging version -- R10's scalar s_load rewrite
// regressed 11.6us: SMEM returns out-of-order so every use pays
// lgkmcnt(0), serializing 128 ~250cy round-trips/wave with no overlap).
// 8 rows/wave, W column in 64 VGPRs, x rows staged 2KB-coalesced into LDS.
__global__ __launch_bounds__(256, 4) void k1_wh(
                      const float* __restrict__ h,
                      const float* __restrict__ ht,
                      const float* __restrict__ W,
                      const float* __restrict__ a1,
                      const float* __restrict__ a2,
                      float* __restrict__ Wh,
                      float* __restrict__ E1p, float* __restrict__ E1n,
                      float* __restrict__ E2p, float* __restrict__ E2n,
                      float* __restrict__ E1i) {
    __shared__ float xs[4][512];                   // per-wave 8 rows x 64 f32
    __shared__ float tr[4][8 * 68];                // per-wave transpose scratch
    __shared__ float ab[128];                      // a1 | a2
    int tid = threadIdx.x;
    int w = tid >> 6, l = tid & 63;
    float wreg[64];
    #pragma unroll
    for (int k = 0; k < 64; ++k) wreg[k] = W[k * 64 + l];
    if (tid < 128) ab[tid] = (tid < 64) ? a1[tid] : a2[tid - 64];
    int rowbase = (blockIdx.x * 4 + w) * 8;        // 8 rows per wave
    int b = rowbase >> 12;
    int m0 = rowbase & (TN - 1);
    const float* srcw = (m0 < NN) ? (ht + ((size_t)b * NN + m0) * DD)
                                  : (h  + ((size_t)b * NN + (m0 - NN)) * DD);
    f32x4 g0 = *reinterpret_cast<const f32x4*>(srcw + l * 8);
    f32x4 g1 = *reinterpret_cast<const f32x4*>(srcw + l * 8 + 4);
    *reinterpret_cast<f32x4*>(&xs[w][l * 8])     = g0;
    *reinterpret_cast<f32x4*>(&xs[w][l * 8 + 4]) = g1;
    __syncthreads();
    float acc8[8];
    #pragma unroll
    for (int r = 0; r < 8; ++r) {
        const f32x4* xr = reinterpret_cast<const f32x4*>(&xs[w][r * 64]);
        float c0 = 0.f, c1 = 0.f, c2 = 0.f, c3 = 0.f;
        #pragma unroll
        for (int k = 0; k < 16; ++k) {
            f32x4 s = xr[k];                       // LDS uniform broadcast
            c0 += s[0] * wreg[k * 4 + 0];
            c1 += s[1] * wreg[k * 4 + 1];
            c2 += s[2] * wreg[k * 4 + 2];
            c3 += s[3] * wreg[k * 4 + 3];
        }
        acc8[r] = (c0 + c1) + (c2 + c3);
        Wh[((size_t)b * TN + m0 + r) * DD + l] = acc8[r];
    }
    // transpose through per-wave LDS (same-wave exchange: no barrier needed)
    #pragma unroll
    for (int r = 0; r < 8; ++r) tr[w][r * 68 + l] = acc8[r];
    int rr = l >> 3, cc = l & 7;
    f32x4 va  = *reinterpret_cast<const f32x4*>(&tr[w][rr * 68 + cc * 8]);
    f32x4 vb  = *reinterpret_cast<const f32x4*>(&tr[w][rr * 68 + cc * 8 + 4]);
    f32x4 a1a = *reinterpret_cast<const f32x4*>(&ab[cc * 8]);
    f32x4 a1b = *reinterpret_cast<const f32x4*>(&ab[cc * 8 + 4]);
    f32x4 a2a = *reinterpret_cast<const f32x4*>(&ab[64 + cc * 8]);
    f32x4 a2b = *reinterpret_cast<const f32x4*>(&ab[64 + cc * 8 + 4]);
    f32x4 s1v = va * a1a + vb * a1b;
    f32x4 s2v = va * a2a + vb * a2b;
    float p1 = (s1v[0] + s1v[1]) + (s1v[2] + s1v[3]);
    float p2 = (s2v[0] + s2v[1]) + (s2v[2] + s2v[3]);
    #pragma unroll
    for (int off = 1; off <= 4; off <<= 1) {
        p1 += __shfl_xor(p1, off, 64);
        p2 += __shfl_xor(p2, off, 64);
    }
    if (cc == 0) {                                 // 8 lanes, rows in parallel
        int mrow = m0 + rr;
        size_t o = (size_t)b * TN + mrow;
        float pp = __expf(p1), pn = __expf(0.2f * p1);
        E1p[o] = pp;
        E1n[o] = pn;
        int sp = (b < 4) ? b       : 8 + (b - 4);
        int sn = (b < 4) ? 4 + b   : 12 + (b - 4);
        E1i[(size_t)mrow * 16 + sp] = pp;
        E1i[(size_t)mrow * 16 + sn] = pn;
        E2p[o] = __expf(p2);
        E2n[o] = __expf(0.2f * p2);
    }
}

// K2 v3: 16-row strips -> grid (8,128,2) = 2048 blocks = 8 blocks/CU
// (was 4): doubles resident waves hiding HBM latency of the ballot-synced
// adj stream. Inner structure (8-deep prefetch, ballot, FMA) unchanged.
// Spart now 128 strips (16 MB).
__global__ __launch_bounds__(256) void k2_mask_stats(
    const float* __restrict__ adj,
    const float* __restrict__ E1i,
    const float* __restrict__ E2p, const float* __restrict__ E2n,
    unsigned long long* __restrict__ qmask,
    float* __restrict__ Spart) {
    int tid = threadIdx.x;
    int w = tid >> 6, l = tid & 63;
    int half = blockIdx.z;
    int j = half * 2048 + blockIdx.x * 256 + tid;   // global column
    int i0 = half * 2048 + blockIdx.y * 16;         // global row base (16-strip)
    f32x4 e2p0, e2p1, e2n0, e2n1;
    #pragma unroll
    for (int b = 0; b < 4; ++b) {
        e2p0[b] = E2p[(size_t)b * TN + j];
        e2n0[b] = E2n[(size_t)b * TN + j];
        e2p1[b] = E2p[(size_t)(b + 4) * TN + j];
        e2n1[b] = E2n[(size_t)(b + 4) * TN + j];
    }
    f32x4 acc0 = {0.f, 0.f, 0.f, 0.f}, acc1 = {0.f, 0.f, 0.f, 0.f};
    const f32x4* e1 = reinterpret_cast<const f32x4*>(E1i + (size_t)i0 * 16);
    float avv[8];
    #pragma unroll
    for (int k = 0; k < 8; ++k)
        avv[k] = adj[(size_t)(i0 + k) * TN + j];
    for (int it8 = 0; it8 < 2; ++it8) {
        float avn[8];
        if (it8 < 1) {
            #pragma unroll
            for (int k = 0; k < 8; ++k)                   // prefetch next round
                avn[k] = adj[(size_t)(i0 + 8 + k) * TN + j];
        }
        #pragma unroll
        for (int k = 0; k < 8; ++k) {
            int ii = it8 * 8 + k;
            unsigned long long bal = __ballot(avv[k] != 0.f);
            if (l == 0)
                qmask[(size_t)(i0 + ii) * 32 + blockIdx.x * 4 + w] = bal;
            f32x4 P0 = e1[ii * 4 + 0];                    // wave-uniform loads
            f32x4 N0 = e1[ii * 4 + 1];
            f32x4 P1 = e1[ii * 4 + 2];
            f32x4 N1 = e1[ii * 4 + 3];
            f32x4 v0 = __builtin_elementwise_max(P0 * e2p0, N0 * e2n0);
            f32x4 v1 = __builtin_elementwise_max(P1 * e2p1, N1 * e2n1);
            acc0 += v0 * avv[k];                          // av in {0,1}: exact mask
            acc1 += v1 * avv[k];
        }
        if (it8 < 1) {
            #pragma unroll
            for (int k = 0; k < 8; ++k) avv[k] = avn[k];
        }
    }
    #pragma unroll
    for (int b = 0; b < 4; ++b) {
        Spart[((size_t)blockIdx.y * 8 + b) * TN + j]     = acc0[b];
        Spart[((size_t)blockIdx.y * 8 + b + 4) * TN + j] = acc1[b];
    }
}

// K3: S = sum(128 strips) + identity term for j>=2048; then
// Whn_t[b][d][j] = Wh[b][j][d]/S[b][j] (bf16, transposed).
__global__ __launch_bounds__(256) void k3_whn(
    const float* __restrict__ Wh,
    const float* __restrict__ Spart,
    const float* __restrict__ E1p, const float* __restrict__ E1n,
    const float* __restrict__ E2p, const float* __restrict__ E2n,
    unsigned short* __restrict__ Wt) {
    __shared__ float tile[64][65];
    __shared__ float ps[4][64];
    __shared__ float rs[64];
    int b = blockIdx.y;
    int j0 = blockIdx.x * 64;
    int tid = threadIdx.x;
    int jj = tid & 63, part = tid >> 6;
    float s = 0.f;
    #pragma unroll
    for (int k = 0; k < 32; ++k) {
        int strip = part * 32 + k;
        s += Spart[((size_t)strip * 8 + b) * TN + j0 + jj];
    }
    ps[part][jj] = s;
    __syncthreads();
    if (tid < 64) {
        float tot = ps[0][tid] + ps[1][tid] + ps[2][tid] + ps[3][tid];
        int j = j0 + tid;
        if (j >= NN) {                 // identity column term (adj TR = I)
            int i = j - NN;
            tot += fmaxf(E1p[(size_t)b * TN + i] * E2p[(size_t)b * TN + j],
                         E1n[(size_t)b * TN + i] * E2n[(size_t)b * TN + j]);
        }
        rs[tid] = 1.0f / tot;
    }
    for (int e = tid; e < 4096; e += 256) {
        int jt = e >> 6, d = e & 63;
        tile[jt][d] = Wh[((size_t)b * TN + j0 + jt) * DD + d];
    }
    __syncthreads();
    for (int e = tid; e < 512; e += 256) {
        int d = e >> 3, jg = e & 7;
        union { unsigned short u[8]; short8 s8; } pk;
        #pragma unroll
        for (int k = 0; k < 8; ++k) {
            int jt = jg * 8 + k;
            pk.u[k] = f2bf(tile[jt][d] * rs[jt]);
        }
        *reinterpret_cast<short8*>(Wt + ((size_t)b * DD + d) * TN + j0 + jg * 8) = pk.s8;
    }
}

// K4 v3: each wave owns 32 i-rows (two 16-row groups acc0/acc1) so every
// B-fragment ds_read_b128 feeds TWO MFMAs. Block covers 128 i-rows; grid
// 1024 (4 blocks/CU). hpq layout unchanged (grp=it*8+w*2+gsel).
__global__ __launch_bounds__(256, 4) void k4_pv(
    const unsigned int* __restrict__ qmask32,
    const float* __restrict__ E1p, const float* __restrict__ E1n,
    const float* __restrict__ E2p, const float* __restrict__ E2n,
    const unsigned short* __restrict__ Wt,
    unsigned short* __restrict__ hpq) {
    __shared__ unsigned short wt_s[64 * 140];
    int bx = blockIdx.x;
    int b  = bx & 7;                 // XCD round-robin
    int js = (bx >> 3) & 3;
    int it = bx >> 5;                // i-tile index 0..31 (128 rows each)
    int i0 = it * 128;
    int half = (it >= 16);           // 0: i<2048 -> j in [0,2048); 1: [2048,4096)
    int tid = threadIdx.x;
    int w = tid >> 6, l = tid & 63;
    int m = l & 15, q = l >> 4;
    int irow0 = i0 + w * 32 + m;     // rows group 0
    int irow1 = irow0 + 16;          // rows group 1
    float e1p0 = E1p[(size_t)b * TN + irow0], e1n0 = E1n[(size_t)b * TN + irow0];
    float e1p1 = E1p[(size_t)b * TN + irow1], e1n1 = E1n[(size_t)b * TN + irow1];
    const float* e2pb = E2p + (size_t)b * TN;
    const float* e2nb = E2n + (size_t)b * TN;
    const unsigned short* wtb = Wt + (size_t)b * DD * TN;
    const unsigned int* mrow0 = qmask32 + (size_t)irow0 * 64;
    const unsigned int* mrow1 = qmask32 + (size_t)irow1 * 64;

    int r0 = tid >> 4, c0 = tid & 15;
    const int jbase = half * 2048 + js * 512;   // global j base
    const int jloc0 = js * 512;                 // local (in-half) bit base

    f32x4 acc0[4], acc1[4];
    #pragma unroll
    for (int dt = 0; dt < 4; ++dt) {
        acc0[dt] = (f32x4){0.f, 0.f, 0.f, 0.f};
        acc1[dt] = (f32x4){0.f, 0.f, 0.f, 0.f};
    }

    // prefetch tile jt=0 + masks jt=0
    short8 g[4];
    #pragma unroll
    for (int k = 0; k < 4; ++k)
        g[k] = *reinterpret_cast<const short8*>(
            wtb + (size_t)(r0 + 16 * k) * TN + jbase + c0 * 8);
    u32x4 m40 = *reinterpret_cast<const u32x4*>(mrow0 + (jloc0 >> 5));
    u32x4 m41 = *reinterpret_cast<const u32x4*>(mrow1 + (jloc0 >> 5));

    for (int jt = 0; jt < 4; ++jt) {
        int j0 = jbase + jt * 128;
        __syncthreads();                // prior reads done
        #pragma unroll
        for (int k = 0; k < 4; ++k)
            *reinterpret_cast<short8*>(&wt_s[(r0 + 16 * k) * 140 + c0 * 8]) = g[k];
        __syncthreads();                // tile visible
        u32x4 m40c = m40, m41c = m41;
        if (jt < 3) {                   // prefetch next tile DURING compute
            #pragma unroll
            for (int k = 0; k < 4; ++k)
                g[k] = *reinterpret_cast<const short8*>(
                    wtb + (size_t)(r0 + 16 * k) * TN + j0 + 128 + c0 * 8);
            m40 = *reinterpret_cast<const u32x4*>(
                mrow0 + ((jloc0 + (jt + 1) * 128) >> 5));
            m41 = *reinterpret_cast<const u32x4*>(
                mrow1 + ((jloc0 + (jt + 1) * 128) >> 5));
        }

        #pragma unroll
        for (int t = 0; t < 4; ++t) {
            int jb = j0 + t * 32 + q * 8;
            f32x4 p20 = *reinterpret_cast<const f32x4*>(e2pb + jb);
            f32x4 p21 = *reinterpret_cast<const f32x4*>(e2pb + jb + 4);
            f32x4 n20 = *reinterpret_cast<const f32x4*>(e2nb + jb);
            f32x4 n21 = *reinterpret_cast<const f32x4*>(e2nb + jb + 4);
            AF af0, af1;
            #pragma unroll
            for (int gsel = 0; gsel < 2; ++gsel) {
                float e1p_v = gsel ? e1p1 : e1p0;
                float e1n_v = gsel ? e1n1 : e1n0;
                unsigned int bytev = ((gsel ? m41c : m40c)[t] >> (q * 8)) & 0xFFu;
                f32x4 v0 = __builtin_elementwise_max(p20 * e1p_v, n20 * e1n_v);
                f32x4 v1 = __builtin_elementwise_max(p21 * e1p_v, n21 * e1n_v);
                union { f32x4 f; u32x4 u; } uv0, uv1;
                uv0.f = v0; uv1.f = v1;
                u32x4 mk0, mk1;
                #pragma unroll
                for (int c = 0; c < 4; ++c) {
                    mk0[c] = (unsigned int)((int)(bytev << (31 - c)) >> 31);
                    mk1[c] = (unsigned int)((int)(bytev << (27 - c)) >> 31);
                }
                uv0.u &= mk0; uv1.u &= mk1;
                __hip_bfloat162 hb0 = __float22bfloat162_rn(make_float2(uv0.f[0], uv0.f[1]));
                __hip_bfloat162 hb1 = __float22bfloat162_rn(make_float2(uv0.f[2], uv0.f[3]));
                __hip_bfloat162 hb2 = __float22bfloat162_rn(make_float2(uv1.f[0], uv1.f[1]));
                __hip_bfloat162 hb3 = __float22bfloat162_rn(make_float2(uv1.f[2], uv1.f[3]));
                AF& af = gsel ? af1 : af0;
                af.u[0] = *reinterpret_cast<unsigned int*>(&hb0);
                af.u[1] = *reinterpret_cast<unsigned int*>(&hb1);
                af.u[2] = *reinterpret_cast<unsigned int*>(&hb2);
                af.u[3] = *reinterpret_cast<unsigned int*>(&hb3);
            }
            #pragma unroll
            for (int dt = 0; dt < 4; ++dt) {
                short8 bf = *reinterpret_cast<const short8*>(
                    &wt_s[(dt * 16 + m) * 140 + t * 32 + q * 8]);   // 1 read, 2 MFMAs
                acc0[dt] = __builtin_amdgcn_mfma_f32_16x16x32_bf16(af0.s8, bf, acc0[dt], 0, 0, 0);
                acc1[dt] = __builtin_amdgcn_mfma_f32_16x16x32_bf16(af1.s8, bf, acc1[dt], 0, 0, 0);
            }
        }
    }

    // Diagonal identity term + epilogue per 16-row group.
    #pragma unroll
    for (int gsel = 0; gsel < 2; ++gsel) {
        f32x4* acc = gsel ? acc1 : acc0;
        int gbase = i0 + w * 32 + gsel * 16 + q * 4;
        if (half == 0 && js == 0) {
            #pragma unroll
            for (int r = 0; r < 4; ++r) {
                int gg = gbase + r;
                float ed = fmaxf(E1p[(size_t)b * TN + gg] * e2pb[gg + NN],
                                 E1n[(size_t)b * TN + gg] * e2nb[gg + NN]);
                #pragma unroll
                for (int dt = 0; dt < 4; ++dt) {
                    int d = dt * 16 + m;
                    acc[dt][r] += ed * bf2f(wtb[(size_t)d * TN + gg + NN]);
                }
            }
        }
        // lane-native bf16 pack; row-group index grp keeps k5 layout intact
        union { unsigned int u[8]; u32x4 v[2]; } pk;
        #pragma unroll
        for (int dt = 0; dt < 4; ++dt) {
            __hip_bfloat162 p0 = __float22bfloat162_rn(make_float2(acc[dt][0], acc[dt][1]));
            __hip_bfloat162 p1 = __float22bfloat162_rn(make_float2(acc[dt][2], acc[dt][3]));
            pk.u[dt * 2 + 0] = *reinterpret_cast<unsigned int*>(&p0);
            pk.u[dt * 2 + 1] = *reinterpret_cast<unsigned int*>(&p1);
        }
        int grp = it * 8 + w * 2 + gsel;           // absolute 16-row group 0..255
        unsigned short* hp = hpq +
            ((((size_t)js * 8 + b) * 256 + grp) * 64 + l) * 16;
        *reinterpret_cast<u32x4*>(hp)     = pk.v[0];
        *reinterpret_cast<u32x4*>(hp + 8) = pk.v[1];
    }
}

// K5: block = (b,it), wave geometry MATCHES k4's writes -> fully coalesced
// u32x4 reads. js-sum in f32, ELU, LDS transpose [64][68], vector f32
// stores with concat remap. 24 MB total traffic.
__global__ __launch_bounds__(256) void k5_epi(const unsigned short* __restrict__ hpq,
                                              float* __restrict__ out) {
    __shared__ float tile[64][68];
    int bx = blockIdx.x;                 // 0..511
    int b  = bx & 7;
    int it = bx >> 3;                    // 0..63
    int tid = threadIdx.x;
    int w = tid >> 6, l = tid & 63;
    int m = l & 15, q = l >> 4;
    const size_t JSTR = (size_t)8 * 64 * 4 * 64 * 16;   // ushorts per js slab
    size_t base = ((((size_t)b * 64 + it) * 4 + w) * 64 + l) * 16;
    float sum[16];
    #pragma unroll
    for (int k = 0; k < 16; ++k) sum[k] = 0.f;
    #pragma unroll
    for (int js = 0; js < 4; ++js) {
        const u32x4* p = reinterpret_cast<const u32x4*>(hpq + js * JSTR + base);
        u32x4 v0 = p[0], v1 = p[1];
        unsigned int uu[8];
        *reinterpret_cast<u32x4*>(&uu[0]) = v0;
        *reinterpret_cast<u32x4*>(&uu[4]) = v1;
        #pragma unroll
        for (int k = 0; k < 16; ++k) {
            int word = (k >> 2) * 2 + ((k >> 1) & 1);
            int hi = k & 1;
            sum[k] += bf2f((unsigned short)((uu[word] >> (hi * 16)) & 0xFFFFu));
        }
    }
    // ELU then scatter into LDS transpose tile: row=w*16+q*4+r, col=dt*16+m
    #pragma unroll
    for (int dt = 0; dt < 4; ++dt) {
        #pragma unroll
        for (int r = 0; r < 4; ++r) {
            float v = sum[dt * 4 + r];
            v = (v > 0.f) ? v : expm1f(v);
            tile[w * 16 + q * 4 + r][dt * 16 + m] = v;
        }
    }
    __syncthreads();
    int rl = tid >> 2, c0 = (tid & 3) * 16;
    int gg = it * 64 + rl;
    int half = (it >= 32);
    int n = gg - half * NN;
    float* orow = out + ((size_t)b * NN + n) * 128 + half * 64 + c0;
    #pragma unroll
    for (int c = 0; c < 4; ++c)
        *reinterpret_cast<f32x4*>(orow + c * 4) =
            *reinterpret_cast<const f32x4*>(&tile[rl][c0 + c * 4]);
}

extern "C" void kernel_launch(void* const* d_in, const int* in_sizes, int n_in,
                              void* d_out, int out_size, void* d_ws, size_t ws_size,
                              hipStream_t stream) {
    const float* h   = (const float*)d_in[0];
    const float* ht  = (const float*)d_in[1];
    const float* W   = (const float*)d_in[2];
    const float* a1  = (const float*)d_in[3];
    const float* a2  = (const float*)d_in[4];
    const float* adj = (const float*)d_in[5];
    float* out = (float*)d_out;

    char* ws = (char*)d_ws;
    float* Wh          = (float*)(ws);                       // 8 MB
    float* Spart       = (float*)(ws + (8 << 20));           // 16 MB (128 strips)
    unsigned short* Wt = (unsigned short*)(ws + (24 << 20)); // 4 MB
    float* E1p         = (float*)(ws + (28 << 20));
    float* E1n         = (float*)(ws + (28 << 20) + (128 << 10));
    float* E2p         = (float*)(ws + (28 << 20) + (256 << 10));
    float* E2n         = (float*)(ws + (28 << 20) + (384 << 10));
    unsigned long long* qmask = (unsigned long long*)(ws + (28 << 20) + (512 << 10)); // 1 MB
    float* E1i         = (float*)(ws + (28 << 20) + (512 << 10) + (2 << 20)); // 256 KB
    const unsigned int* qmask32 = (const unsigned int*)qmask;
    // 4 bf16 partial slabs (4 MB each, lane-native layout) overlay Wh + low
    // half of Spart -- both dead before k4 writes hpq.
    unsigned short* hpq = (unsigned short*)ws;               // 16 MB total

    k1_wh<<<dim3(BB * TN / 32), dim3(256), 0, stream>>>(h, ht, W, a1, a2, Wh,
                                                        E1p, E1n, E2p, E2n, E1i);
    k2_mask_stats<<<dim3(8, 128, 2), dim3(256), 0, stream>>>(adj, E1i, E2p, E2n,
                                                             qmask, Spart);
    k3_whn<<<dim3(64, 8), dim3(256), 0, stream>>>(Wh, Spart, E1p, E1n, E2p, E2n, Wt);
    k4_pv<<<dim3(1024), dim3(256), 0, stream>>>(qmask32, E1p, E1n, E2p, E2n, Wt,
                                                hpq);
    k5_epi<<<dim3(512), dim3(256), 0, stream>>>(hpq, out);
}

// Round 12
// 170.814 us; speedup vs baseline: 1.0443x; 1.0022x over previous
//
#include <hip/hip_runtime.h>
#include <hip/hip_bf16.h>
#include <math.h>

#define BB 8
#define NN 2048
#define TN 4096
#define DD 64

typedef __attribute__((ext_vector_type(8))) short short8;
typedef __attribute__((ext_vector_type(4))) float f32x4;
typedef __attribute__((ext_vector_type(4))) unsigned int u32x4;

union AF { unsigned int u[4]; short8 s8; };

__device__ __forceinline__ unsigned short f2bf(float f) {
    union { float f; unsigned int i; } v; v.f = f;
    unsigned int r = v.i + 0x7FFF + ((v.i >> 16) & 1);   // RNE
    return (unsigned short)(r >> 16);
}
__device__ __forceinline__ float bf2f(unsigned short u) {
    union { unsigned int i; float f; } v; v.i = ((unsigned int)u) << 16; return v.f;
}

// K1 (R8 LDS-staging version): 8 rows/wave, W column in 64 VGPRs, x rows
// staged 2KB-coalesced into LDS then broadcast; a1/a2 reduction via LDS
// transpose; epilogue exp/stores on 8 lanes in parallel.
__global__ __launch_bounds__(256, 4) void k1_wh(
                      const float* __restrict__ h,
                      const float* __restrict__ ht,
                      const float* __restrict__ W,
                      const float* __restrict__ a1,
                      const float* __restrict__ a2,
                      float* __restrict__ Wh,
                      float* __restrict__ E1p, float* __restrict__ E1n,
                      float* __restrict__ E2p, float* __restrict__ E2n,
                      float* __restrict__ E1i) {
    __shared__ float xs[4][512];                   // per-wave 8 rows x 64 f32
    __shared__ float tr[4][8 * 68];                // per-wave transpose scratch
    __shared__ float ab[128];                      // a1 | a2
    int tid = threadIdx.x;
    int w = tid >> 6, l = tid & 63;
    float wreg[64];
    #pragma unroll
    for (int k = 0; k < 64; ++k) wreg[k] = W[k * 64 + l];
    if (tid < 128) ab[tid] = (tid < 64) ? a1[tid] : a2[tid - 64];
    int rowbase = (blockIdx.x * 4 + w) * 8;        // 8 rows per wave
    int b = rowbase >> 12;
    int m0 = rowbase & (TN - 1);
    const float* srcw = (m0 < NN) ? (ht + ((size_t)b * NN + m0) * DD)
                                  : (h  + ((size_t)b * NN + (m0 - NN)) * DD);
    f32x4 g0 = *reinterpret_cast<const f32x4*>(srcw + l * 8);
    f32x4 g1 = *reinterpret_cast<const f32x4*>(srcw + l * 8 + 4);
    *reinterpret_cast<f32x4*>(&xs[w][l * 8])     = g0;
    *reinterpret_cast<f32x4*>(&xs[w][l * 8 + 4]) = g1;
    __syncthreads();
    float acc8[8];
    #pragma unroll
    for (int r = 0; r < 8; ++r) {
        const f32x4* xr = reinterpret_cast<const f32x4*>(&xs[w][r * 64]);
        float c0 = 0.f, c1 = 0.f, c2 = 0.f, c3 = 0.f;
        #pragma unroll
        for (int k = 0; k < 16; ++k) {
            f32x4 s = xr[k];                       // LDS uniform broadcast
            c0 += s[0] * wreg[k * 4 + 0];
            c1 += s[1] * wreg[k * 4 + 1];
            c2 += s[2] * wreg[k * 4 + 2];
            c3 += s[3] * wreg[k * 4 + 3];
        }
        acc8[r] = (c0 + c1) + (c2 + c3);
        Wh[((size_t)b * TN + m0 + r) * DD + l] = acc8[r];
    }
    // transpose through per-wave LDS (same-wave exchange: no barrier needed)
    #pragma unroll
    for (int r = 0; r < 8; ++r) tr[w][r * 68 + l] = acc8[r];
    int rr = l >> 3, cc = l & 7;
    f32x4 va  = *reinterpret_cast<const f32x4*>(&tr[w][rr * 68 + cc * 8]);
    f32x4 vb  = *reinterpret_cast<const f32x4*>(&tr[w][rr * 68 + cc * 8 + 4]);
    f32x4 a1a = *reinterpret_cast<const f32x4*>(&ab[cc * 8]);
    f32x4 a1b = *reinterpret_cast<const f32x4*>(&ab[cc * 8 + 4]);
    f32x4 a2a = *reinterpret_cast<const f32x4*>(&ab[64 + cc * 8]);
    f32x4 a2b = *reinterpret_cast<const f32x4*>(&ab[64 + cc * 8 + 4]);
    f32x4 s1v = va * a1a + vb * a1b;
    f32x4 s2v = va * a2a + vb * a2b;
    float p1 = (s1v[0] + s1v[1]) + (s1v[2] + s1v[3]);
    float p2 = (s2v[0] + s2v[1]) + (s2v[2] + s2v[3]);
    #pragma unroll
    for (int off = 1; off <= 4; off <<= 1) {
        p1 += __shfl_xor(p1, off, 64);
        p2 += __shfl_xor(p2, off, 64);
    }
    if (cc == 0) {                                 // 8 lanes, rows in parallel
        int mrow = m0 + rr;
        size_t o = (size_t)b * TN + mrow;
        float pp = __expf(p1), pn = __expf(0.2f * p1);
        E1p[o] = pp;
        E1n[o] = pn;
        int sp = (b < 4) ? b       : 8 + (b - 4);
        int sn = (b < 4) ? 4 + b   : 12 + (b - 4);
        E1i[(size_t)mrow * 16 + sp] = pp;
        E1i[(size_t)mrow * 16 + sn] = pn;
        E2p[o] = __expf(p2);
        E2n[o] = __expf(0.2f * p2);
    }
}

// K2 v4: 64-row strips -> grid (8,32,2) = 512 blocks. R11 proved k2 is
// BANDWIDTH-bound (its +4.4us matched the +33MB overhead traffic exactly),
// so HALVING overhead traffic vs R8 (Spart 8->4MB, e2 block-loads
// 16.8->8.4MB) is the right direction. In-flight check at 2 blocks/CU:
// 8 waves x 8-deep prefetch x 256B = 16KB/CU > ~9.2KB needed at 900cy HBM
// latency -- still BW-feasible; no barriers to serialize on.
__global__ __launch_bounds__(256) void k2_mask_stats(
    const float* __restrict__ adj,
    const float* __restrict__ E1i,
    const float* __restrict__ E2p, const float* __restrict__ E2n,
    unsigned long long* __restrict__ qmask,
    float* __restrict__ Spart) {
    int tid = threadIdx.x;
    int w = tid >> 6, l = tid & 63;
    int half = blockIdx.z;
    int j = half * 2048 + blockIdx.x * 256 + tid;   // global column
    int i0 = half * 2048 + blockIdx.y * 64;         // global row base (64-strip)
    f32x4 e2p0, e2p1, e2n0, e2n1;
    #pragma unroll
    for (int b = 0; b < 4; ++b) {
        e2p0[b] = E2p[(size_t)b * TN + j];
        e2n0[b] = E2n[(size_t)b * TN + j];
        e2p1[b] = E2p[(size_t)(b + 4) * TN + j];
        e2n1[b] = E2n[(size_t)(b + 4) * TN + j];
    }
    f32x4 acc0 = {0.f, 0.f, 0.f, 0.f}, acc1 = {0.f, 0.f, 0.f, 0.f};
    const f32x4* e1 = reinterpret_cast<const f32x4*>(E1i + (size_t)i0 * 16);
    float avv[8];
    #pragma unroll
    for (int k = 0; k < 8; ++k)
        avv[k] = adj[(size_t)(i0 + k) * TN + j];
    for (int it8 = 0; it8 < 8; ++it8) {
        float avn[8];
        if (it8 < 7) {
            #pragma unroll
            for (int k = 0; k < 8; ++k)                   // prefetch next round
                avn[k] = adj[(size_t)(i0 + (it8 + 1) * 8 + k) * TN + j];
        }
        #pragma unroll
        for (int k = 0; k < 8; ++k) {
            int ii = it8 * 8 + k;
            unsigned long long bal = __ballot(avv[k] != 0.f);
            if (l == 0)
                qmask[(size_t)(i0 + ii) * 32 + blockIdx.x * 4 + w] = bal;
            f32x4 P0 = e1[ii * 4 + 0];                    // wave-uniform loads
            f32x4 N0 = e1[ii * 4 + 1];
            f32x4 P1 = e1[ii * 4 + 2];
            f32x4 N1 = e1[ii * 4 + 3];
            f32x4 v0 = __builtin_elementwise_max(P0 * e2p0, N0 * e2n0);
            f32x4 v1 = __builtin_elementwise_max(P1 * e2p1, N1 * e2n1);
            acc0 += v0 * avv[k];                          // av in {0,1}: exact mask
            acc1 += v1 * avv[k];
        }
        if (it8 < 7) {
            #pragma unroll
            for (int k = 0; k < 8; ++k) avv[k] = avn[k];
        }
    }
    #pragma unroll
    for (int b = 0; b < 4; ++b) {
        Spart[((size_t)blockIdx.y * 8 + b) * TN + j]     = acc0[b];
        Spart[((size_t)blockIdx.y * 8 + b + 4) * TN + j] = acc1[b];
    }
}

// K3: S = sum(32 strips) + identity term for j>=2048; then
// Whn_t[b][d][j] = Wh[b][j][d]/S[b][j] (bf16, transposed).
__global__ __launch_bounds__(256) void k3_whn(
    const float* __restrict__ Wh,
    const float* __restrict__ Spart,
    const float* __restrict__ E1p, const float* __restrict__ E1n,
    const float* __restrict__ E2p, const float* __restrict__ E2n,
    unsigned short* __restrict__ Wt) {
    __shared__ float tile[64][65];
    __shared__ float ps[4][64];
    __shared__ float rs[64];
    int b = blockIdx.y;
    int j0 = blockIdx.x * 64;
    int tid = threadIdx.x;
    int jj = tid & 63, part = tid >> 6;
    float s = 0.f;
    #pragma unroll
    for (int k = 0; k < 8; ++k) {
        int strip = part * 8 + k;
        s += Spart[((size_t)strip * 8 + b) * TN + j0 + jj];
    }
    ps[part][jj] = s;
    __syncthreads();
    if (tid < 64) {
        float tot = ps[0][tid] + ps[1][tid] + ps[2][tid] + ps[3][tid];
        int j = j0 + tid;
        if (j >= NN) {                 // identity column term (adj TR = I)
            int i = j - NN;
            tot += fmaxf(E1p[(size_t)b * TN + i] * E2p[(size_t)b * TN + j],
                         E1n[(size_t)b * TN + i] * E2n[(size_t)b * TN + j]);
        }
        rs[tid] = 1.0f / tot;
    }
    for (int e = tid; e < 4096; e += 256) {
        int jt = e >> 6, d = e & 63;
        tile[jt][d] = Wh[((size_t)b * TN + j0 + jt) * DD + d];
    }
    __syncthreads();
    for (int e = tid; e < 512; e += 256) {
        int d = e >> 3, jg = e & 7;
        union { unsigned short u[8]; short8 s8; } pk;
        #pragma unroll
        for (int k = 0; k < 8; ++k) {
            int jt = jg * 8 + k;
            pk.u[k] = f2bf(tile[jt][d] * rs[jt]);
        }
        *reinterpret_cast<short8*>(Wt + ((size_t)b * DD + d) * TN + j0 + jg * 8) = pk.s8;
    }
}

// K4 v3: each wave owns 32 i-rows (two 16-row groups acc0/acc1) so every
// B-fragment ds_read_b128 feeds TWO MFMAs. Block covers 128 i-rows; grid
// 1024 (4 blocks/CU). hpq layout unchanged (grp=it*8+w*2+gsel).
__global__ __launch_bounds__(256, 4) void k4_pv(
    const unsigned int* __restrict__ qmask32,
    const float* __restrict__ E1p, const float* __restrict__ E1n,
    const float* __restrict__ E2p, const float* __restrict__ E2n,
    const unsigned short* __restrict__ Wt,
    unsigned short* __restrict__ hpq) {
    __shared__ unsigned short wt_s[64 * 140];
    int bx = blockIdx.x;
    int b  = bx & 7;                 // XCD round-robin
    int js = (bx >> 3) & 3;
    int it = bx >> 5;                // i-tile index 0..31 (128 rows each)
    int i0 = it * 128;
    int half = (it >= 16);           // 0: i<2048 -> j in [0,2048); 1: [2048,4096)
    int tid = threadIdx.x;
    int w = tid >> 6, l = tid & 63;
    int m = l & 15, q = l >> 4;
    int irow0 = i0 + w * 32 + m;     // rows group 0
    int irow1 = irow0 + 16;          // rows group 1
    float e1p0 = E1p[(size_t)b * TN + irow0], e1n0 = E1n[(size_t)b * TN + irow0];
    float e1p1 = E1p[(size_t)b * TN + irow1], e1n1 = E1n[(size_t)b * TN + irow1];
    const float* e2pb = E2p + (size_t)b * TN;
    const float* e2nb = E2n + (size_t)b * TN;
    const unsigned short* wtb = Wt + (size_t)b * DD * TN;
    const unsigned int* mrow0 = qmask32 + (size_t)irow0 * 64;
    const unsigned int* mrow1 = qmask32 + (size_t)irow1 * 64;

    int r0 = tid >> 4, c0 = tid & 15;
    const int jbase = half * 2048 + js * 512;   // global j base
    const int jloc0 = js * 512;                 // local (in-half) bit base

    f32x4 acc0[4], acc1[4];
    #pragma unroll
    for (int dt = 0; dt < 4; ++dt) {
        acc0[dt] = (f32x4){0.f, 0.f, 0.f, 0.f};
        acc1[dt] = (f32x4){0.f, 0.f, 0.f, 0.f};
    }

    // prefetch tile jt=0 + masks jt=0
    short8 g[4];
    #pragma unroll
    for (int k = 0; k < 4; ++k)
        g[k] = *reinterpret_cast<const short8*>(
            wtb + (size_t)(r0 + 16 * k) * TN + jbase + c0 * 8);
    u32x4 m40 = *reinterpret_cast<const u32x4*>(mrow0 + (jloc0 >> 5));
    u32x4 m41 = *reinterpret_cast<const u32x4*>(mrow1 + (jloc0 >> 5));

    for (int jt = 0; jt < 4; ++jt) {
        int j0 = jbase + jt * 128;
        __syncthreads();                // prior reads done
        #pragma unroll
        for (int k = 0; k < 4; ++k)
            *reinterpret_cast<short8*>(&wt_s[(r0 + 16 * k) * 140 + c0 * 8]) = g[k];
        __syncthreads();                // tile visible
        u32x4 m40c = m40, m41c = m41;
        if (jt < 3) {                   // prefetch next tile DURING compute
            #pragma unroll
            for (int k = 0; k < 4; ++k)
                g[k] = *reinterpret_cast<const short8*>(
                    wtb + (size_t)(r0 + 16 * k) * TN + j0 + 128 + c0 * 8);
            m40 = *reinterpret_cast<const u32x4*>(
                mrow0 + ((jloc0 + (jt + 1) * 128) >> 5));
            m41 = *reinterpret_cast<const u32x4*>(
                mrow1 + ((jloc0 + (jt + 1) * 128) >> 5));
        }

        #pragma unroll
        for (int t = 0; t < 4; ++t) {
            int jb = j0 + t * 32 + q * 8;
            f32x4 p20 = *reinterpret_cast<const f32x4*>(e2pb + jb);
            f32x4 p21 = *reinterpret_cast<const f32x4*>(e2pb + jb + 4);
            f32x4 n20 = *reinterpret_cast<const f32x4*>(e2nb + jb);
            f32x4 n21 = *reinterpret_cast<const f32x4*>(e2nb + jb + 4);
            AF af0, af1;
            #pragma unroll
            for (int gsel = 0; gsel < 2; ++gsel) {
                float e1p_v = gsel ? e1p1 : e1p0;
                float e1n_v = gsel ? e1n1 : e1n0;
                unsigned int bytev = ((gsel ? m41c : m40c)[t] >> (q * 8)) & 0xFFu;
                f32x4 v0 = __builtin_elementwise_max(p20 * e1p_v, n20 * e1n_v);
                f32x4 v1 = __builtin_elementwise_max(p21 * e1p_v, n21 * e1n_v);
                union { f32x4 f; u32x4 u; } uv0, uv1;
                uv0.f = v0; uv1.f = v1;
                u32x4 mk0, mk1;
                #pragma unroll
                for (int c = 0; c < 4; ++c) {
                    mk0[c] = (unsigned int)((int)(bytev << (31 - c)) >> 31);
                    mk1[c] = (unsigned int)((int)(bytev << (27 - c)) >> 31);
                }
                uv0.u &= mk0; uv1.u &= mk1;
                __hip_bfloat162 hb0 = __float22bfloat162_rn(make_float2(uv0.f[0], uv0.f[1]));
                __hip_bfloat162 hb1 = __float22bfloat162_rn(make_float2(uv0.f[2], uv0.f[3]));
                __hip_bfloat162 hb2 = __float22bfloat162_rn(make_float2(uv1.f[0], uv1.f[1]));
                __hip_bfloat162 hb3 = __float22bfloat162_rn(make_float2(uv1.f[2], uv1.f[3]));
                AF& af = gsel ? af1 : af0;
                af.u[0] = *reinterpret_cast<unsigned int*>(&hb0);
                af.u[1] = *reinterpret_cast<unsigned int*>(&hb1);
                af.u[2] = *reinterpret_cast<unsigned int*>(&hb2);
                af.u[3] = *reinterpret_cast<unsigned int*>(&hb3);
            }
            #pragma unroll
            for (int dt = 0; dt < 4; ++dt) {
                short8 bf = *reinterpret_cast<const short8*>(
                    &wt_s[(dt * 16 + m) * 140 + t * 32 + q * 8]);   // 1 read, 2 MFMAs
                acc0[dt] = __builtin_amdgcn_mfma_f32_16x16x32_bf16(af0.s8, bf, acc0[dt], 0, 0, 0);
                acc1[dt] = __builtin_amdgcn_mfma_f32_16x16x32_bf16(af1.s8, bf, acc1[dt], 0, 0, 0);
            }
        }
    }

    // Diagonal identity term + epilogue per 16-row group.
    #pragma unroll
    for (int gsel = 0; gsel < 2; ++gsel) {
        f32x4* acc = gsel ? acc1 : acc0;
        int gbase = i0 + w * 32 + gsel * 16 + q * 4;
        if (half == 0 && js == 0) {
            #pragma unroll
            for (int r = 0; r < 4; ++r) {
                int gg = gbase + r;
                float ed = fmaxf(E1p[(size_t)b * TN + gg] * e2pb[gg + NN],
                                 E1n[(size_t)b * TN + gg] * e2nb[gg + NN]);
                #pragma unroll
                for (int dt = 0; dt < 4; ++dt) {
                    int d = dt * 16 + m;
                    acc[dt][r] += ed * bf2f(wtb[(size_t)d * TN + gg + NN]);
                }
            }
        }
        // lane-native bf16 pack; row-group index grp keeps k5 layout intact
        union { unsigned int u[8]; u32x4 v[2]; } pk;
        #pragma unroll
        for (int dt = 0; dt < 4; ++dt) {
            __hip_bfloat162 p0 = __float22bfloat162_rn(make_float2(acc[dt][0], acc[dt][1]));
            __hip_bfloat162 p1 = __float22bfloat162_rn(make_float2(acc[dt][2], acc[dt][3]));
            pk.u[dt * 2 + 0] = *reinterpret_cast<unsigned int*>(&p0);
            pk.u[dt * 2 + 1] = *reinterpret_cast<unsigned int*>(&p1);
        }
        int grp = it * 8 + w * 2 + gsel;           // absolute 16-row group 0..255
        unsigned short* hp = hpq +
            ((((size_t)js * 8 + b) * 256 + grp) * 64 + l) * 16;
        *reinterpret_cast<u32x4*>(hp)     = pk.v[0];
        *reinterpret_cast<u32x4*>(hp + 8) = pk.v[1];
    }
}

// K5: block = (b,it), wave geometry MATCHES k4's writes -> fully coalesced
// u32x4 reads. js-sum in f32, ELU, LDS transpose [64][68], vector f32
// stores with concat remap. 24 MB total traffic.
__global__ __launch_bounds__(256) void k5_epi(const unsigned short* __restrict__ hpq,
                                              float* __restrict__ out) {
    __shared__ float tile[64][68];
    int bx = blockIdx.x;                 // 0..511
    int b  = bx & 7;
    int it = bx >> 3;                    // 0..63
    int tid = threadIdx.x;
    int w = tid >> 6, l = tid & 63;
    int m = l & 15, q = l >> 4;
    const size_t JSTR = (size_t)8 * 64 * 4 * 64 * 16;   // ushorts per js slab
    size_t base = ((((size_t)b * 64 + it) * 4 + w) * 64 + l) * 16;
    float sum[16];
    #pragma unroll
    for (int k = 0; k < 16; ++k) sum[k] = 0.f;
    #pragma unroll
    for (int js = 0; js < 4; ++js) {
        const u32x4* p = reinterpret_cast<const u32x4*>(hpq + js * JSTR + base);
        u32x4 v0 = p[0], v1 = p[1];
        unsigned int uu[8];
        *reinterpret_cast<u32x4*>(&uu[0]) = v0;
        *reinterpret_cast<u32x4*>(&uu[4]) = v1;
        #pragma unroll
        for (int k = 0; k < 16; ++k) {
            int word = (k >> 2) * 2 + ((k >> 1) & 1);
            int hi = k & 1;
            sum[k] += bf2f((unsigned short)((uu[word] >> (hi * 16)) & 0xFFFFu));
        }
    }
    // ELU then scatter into LDS transpose tile: row=w*16+q*4+r, col=dt*16+m
    #pragma unroll
    for (int dt = 0; dt < 4; ++dt) {
        #pragma unroll
        for (int r = 0; r < 4; ++r) {
            float v = sum[dt * 4 + r];
            v = (v > 0.f) ? v : expm1f(v);
            tile[w * 16 + q * 4 + r][dt * 16 + m] = v;
        }
    }
    __syncthreads();
    int rl = tid >> 2, c0 = (tid & 3) * 16;
    int gg = it * 64 + rl;
    int half = (it >= 32);
    int n = gg - half * NN;
    float* orow = out + ((size_t)b * NN + n) * 128 + half * 64 + c0;
    #pragma unroll
    for (int c = 0; c < 4; ++c)
        *reinterpret_cast<f32x4*>(orow + c * 4) =
            *reinterpret_cast<const f32x4*>(&tile[rl][c0 + c * 4]);
}

extern "C" void kernel_launch(void* const* d_in, const int* in_sizes, int n_in,
                              void* d_out, int out_size, void* d_ws, size_t ws_size,
                              hipStream_t stream) {
    const float* h   = (const float*)d_in[0];
    const float* ht  = (const float*)d_in[1];
    const float* W   = (const float*)d_in[2];
    const float* a1  = (const float*)d_in[3];
    const float* a2  = (const float*)d_in[4];
    const float* adj = (const float*)d_in[5];
    float* out = (float*)d_out;

    char* ws = (char*)d_ws;
    float* Wh          = (float*)(ws);                       // 8 MB
    float* Spart       = (float*)(ws + (8 << 20));           // 4 MB (32 strips)
    unsigned short* Wt = (unsigned short*)(ws + (16 << 20)); // 4 MB
    float* E1p         = (float*)(ws + (20 << 20));
    float* E1n         = (float*)(ws + (20 << 20) + (128 << 10));
    float* E2p         = (float*)(ws + (20 << 20) + (256 << 10));
    float* E2n         = (float*)(ws + (20 << 20) + (384 << 10));
    unsigned long long* qmask = (unsigned long long*)(ws + (20 << 20) + (512 << 10)); // 1 MB
    float* E1i         = (float*)(ws + (20 << 20) + (512 << 10) + (2 << 20)); // 256 KB
    const unsigned int* qmask32 = (const unsigned int*)qmask;
    // 4 bf16 partial slabs (4 MB each, lane-native layout) overlay Wh+Spart
    unsigned short* hpq = (unsigned short*)ws;               // 16 MB total

    k1_wh<<<dim3(BB * TN / 32), dim3(256), 0, stream>>>(h, ht, W, a1, a2, Wh,
                                                        E1p, E1n, E2p, E2n, E1i);
    k2_mask_stats<<<dim3(8, 32, 2), dim3(256), 0, stream>>>(adj, E1i, E2p, E2n,
                                                            qmask, Spart);
    k3_whn<<<dim3(64, 8), dim3(256), 0, stream>>>(Wh, Spart, E1p, E1n, E2p, E2n, Wt);
    k4_pv<<<dim3(1024), dim3(256), 0, stream>>>(qmask32, E1p, E1n, E2p, E2n, Wt,
                                                hpq);
    k5_epi<<<dim3(512), dim3(256), 0, stream>>>(hpq, out);
}

// Round 13
// 165.701 us; speedup vs baseline: 1.0765x; 1.0309x over previous
//
#include <hip/hip_runtime.h>
#include <hip/hip_bf16.h>
#include <math.h>

#define BB 8
#define NN 2048
#define TN 4096
#define DD 64

typedef __attribute__((ext_vector_type(8))) short short8;
typedef __attribute__((ext_vector_type(4))) float f32x4;
typedef __attribute__((ext_vector_type(4))) unsigned int u32x4;

union AF { unsigned int u[4]; short8 s8; };

__device__ __forceinline__ unsigned short f2bf(float f) {
    union { float f; unsigned int i; } v; v.f = f;
    unsigned int r = v.i + 0x7FFF + ((v.i >> 16) & 1);   // RNE
    return (unsigned short)(r >> 16);
}
__device__ __forceinline__ float bf2f(unsigned short u) {
    union { unsigned int i; float f; } v; v.i = ((unsigned int)u) << 16; return v.f;
}

// K1: Wh = concat(ht,h) @ W (f32); s1 = Wh@a1, s2 = Wh@a2; exp tables.
// 8 rows/wave, W column in 64 VGPRs; a1/a2 reduction via LDS transpose,
// epilogue exp/stores on 8 lanes in parallel.
__global__ __launch_bounds__(256, 4) void k1_wh(
                      const float* __restrict__ h,
                      const float* __restrict__ ht,
                      const float* __restrict__ W,
                      const float* __restrict__ a1,
                      const float* __restrict__ a2,
                      float* __restrict__ Wh,
                      float* __restrict__ E1p, float* __restrict__ E1n,
                      float* __restrict__ E2p, float* __restrict__ E2n,
                      float* __restrict__ E1i) {
    __shared__ float xs[4][512];                   // per-wave 8 rows x 64 f32
    __shared__ float tr[4][8 * 68];                // per-wave transpose scratch
    __shared__ float ab[128];                      // a1 | a2
    int tid = threadIdx.x;
    int w = tid >> 6, l = tid & 63;
    float wreg[64];
    #pragma unroll
    for (int k = 0; k < 64; ++k) wreg[k] = W[k * 64 + l];
    if (tid < 128) ab[tid] = (tid < 64) ? a1[tid] : a2[tid - 64];
    int rowbase = (blockIdx.x * 4 + w) * 8;        // 8 rows per wave
    int b = rowbase >> 12;
    int m0 = rowbase & (TN - 1);
    const float* srcw = (m0 < NN) ? (ht + ((size_t)b * NN + m0) * DD)
                                  : (h  + ((size_t)b * NN + (m0 - NN)) * DD);
    f32x4 g0 = *reinterpret_cast<const f32x4*>(srcw + l * 8);
    f32x4 g1 = *reinterpret_cast<const f32x4*>(srcw + l * 8 + 4);
    *reinterpret_cast<f32x4*>(&xs[w][l * 8])     = g0;
    *reinterpret_cast<f32x4*>(&xs[w][l * 8 + 4]) = g1;
    __syncthreads();
    float acc8[8];
    #pragma unroll
    for (int r = 0; r < 8; ++r) {
        const f32x4* xr = reinterpret_cast<const f32x4*>(&xs[w][r * 64]);
        float c0 = 0.f, c1 = 0.f, c2 = 0.f, c3 = 0.f;
        #pragma unroll
        for (int k = 0; k < 16; ++k) {
            f32x4 s = xr[k];                       // LDS uniform broadcast
            c0 += s[0] * wreg[k * 4 + 0];
            c1 += s[1] * wreg[k * 4 + 1];
            c2 += s[2] * wreg[k * 4 + 2];
            c3 += s[3] * wreg[k * 4 + 3];
        }
        acc8[r] = (c0 + c1) + (c2 + c3);
        Wh[((size_t)b * TN + m0 + r) * DD + l] = acc8[r];
    }
    // transpose through per-wave LDS (same-wave exchange: no barrier needed)
    #pragma unroll
    for (int r = 0; r < 8; ++r) tr[w][r * 68 + l] = acc8[r];
    int rr = l >> 3, cc = l & 7;
    f32x4 va  = *reinterpret_cast<const f32x4*>(&tr[w][rr * 68 + cc * 8]);
    f32x4 vb  = *reinterpret_cast<const f32x4*>(&tr[w][rr * 68 + cc * 8 + 4]);
    f32x4 a1a = *reinterpret_cast<const f32x4*>(&ab[cc * 8]);
    f32x4 a1b = *reinterpret_cast<const f32x4*>(&ab[cc * 8 + 4]);
    f32x4 a2a = *reinterpret_cast<const f32x4*>(&ab[64 + cc * 8]);
    f32x4 a2b = *reinterpret_cast<const f32x4*>(&ab[64 + cc * 8 + 4]);
    f32x4 s1v = va * a1a + vb * a1b;
    f32x4 s2v = va * a2a + vb * a2b;
    float p1 = (s1v[0] + s1v[1]) + (s1v[2] + s1v[3]);
    float p2 = (s2v[0] + s2v[1]) + (s2v[2] + s2v[3]);
    #pragma unroll
    for (int off = 1; off <= 4; off <<= 1) {
        p1 += __shfl_xor(p1, off, 64);
        p2 += __shfl_xor(p2, off, 64);
    }
    if (cc == 0) {                                 // 8 lanes, rows in parallel
        int mrow = m0 + rr;
        size_t o = (size_t)b * TN + mrow;
        float pp = __expf(p1), pn = __expf(0.2f * p1);
        E1p[o] = pp;
        E1n[o] = pn;
        int sp = (b < 4) ? b       : 8 + (b - 4);
        int sn = (b < 4) ? 4 + b   : 12 + (b - 4);
        E1i[(size_t)mrow * 16 + sp] = pp;
        E1i[(size_t)mrow * 16 + sn] = pn;
        E2p[o] = __expf(p2);
        E2n[o] = __expf(0.2f * p2);
    }
}

// K2: stream ONLY dense quadrants TL/BR. 32-row strips, grid (8,64,2)=1024
// blocks (4/CU). Software-pipelined it8 loop (16 loads in flight).
// Strip size 32 is a measured local optimum: 16-row (+4.4us, overhead
// traffic, BW-bound) and 64-row (+4.0us, 2 blocks/CU latency) both worse.
__global__ __launch_bounds__(256) void k2_mask_stats(
    const float* __restrict__ adj,
    const float* __restrict__ E1i,
    const float* __restrict__ E2p, const float* __restrict__ E2n,
    unsigned long long* __restrict__ qmask,
    float* __restrict__ Spart) {
    int tid = threadIdx.x;
    int w = tid >> 6, l = tid & 63;
    int half = blockIdx.z;
    int j = half * 2048 + blockIdx.x * 256 + tid;   // global column
    int i0 = half * 2048 + blockIdx.y * 32;         // global row base (32-strip)
    f32x4 e2p0, e2p1, e2n0, e2n1;
    #pragma unroll
    for (int b = 0; b < 4; ++b) {
        e2p0[b] = E2p[(size_t)b * TN + j];
        e2n0[b] = E2n[(size_t)b * TN + j];
        e2p1[b] = E2p[(size_t)(b + 4) * TN + j];
        e2n1[b] = E2n[(size_t)(b + 4) * TN + j];
    }
    f32x4 acc0 = {0.f, 0.f, 0.f, 0.f}, acc1 = {0.f, 0.f, 0.f, 0.f};
    const f32x4* e1 = reinterpret_cast<const f32x4*>(E1i + (size_t)i0 * 16);
    float avv[8];
    #pragma unroll
    for (int k = 0; k < 8; ++k)
        avv[k] = adj[(size_t)(i0 + k) * TN + j];
    for (int it8 = 0; it8 < 4; ++it8) {
        float avn[8];
        if (it8 < 3) {
            #pragma unroll
            for (int k = 0; k < 8; ++k)                   // prefetch next round
                avn[k] = adj[(size_t)(i0 + (it8 + 1) * 8 + k) * TN + j];
        }
        #pragma unroll
        for (int k = 0; k < 8; ++k) {
            int ii = it8 * 8 + k;
            unsigned long long bal = __ballot(avv[k] != 0.f);
            if (l == 0)
                qmask[(size_t)(i0 + ii) * 32 + blockIdx.x * 4 + w] = bal;
            f32x4 P0 = e1[ii * 4 + 0];                    // wave-uniform loads
            f32x4 N0 = e1[ii * 4 + 1];
            f32x4 P1 = e1[ii * 4 + 2];
            f32x4 N1 = e1[ii * 4 + 3];
            f32x4 v0 = __builtin_elementwise_max(P0 * e2p0, N0 * e2n0);
            f32x4 v1 = __builtin_elementwise_max(P1 * e2p1, N1 * e2n1);
            acc0 += v0 * avv[k];                          // av in {0,1}: exact mask
            acc1 += v1 * avv[k];
        }
        if (it8 < 3) {
            #pragma unroll
            for (int k = 0; k < 8; ++k) avv[k] = avn[k];
        }
    }
    #pragma unroll
    for (int b = 0; b < 4; ++b) {
        Spart[((size_t)blockIdx.y * 8 + b) * TN + j]     = acc0[b];
        Spart[((size_t)blockIdx.y * 8 + b + 4) * TN + j] = acc1[b];
    }
}

// K3: S = sum(64 strips) + identity term for j>=2048; then
// Whn_t[b][d][j] = Wh[b][j][d]/S[b][j] (bf16, transposed).
__global__ __launch_bounds__(256) void k3_whn(
    const float* __restrict__ Wh,
    const float* __restrict__ Spart,
    const float* __restrict__ E1p, const float* __restrict__ E1n,
    const float* __restrict__ E2p, const float* __restrict__ E2n,
    unsigned short* __restrict__ Wt) {
    __shared__ float tile[64][65];
    __shared__ float ps[4][64];
    __shared__ float rs[64];
    int b = blockIdx.y;
    int j0 = blockIdx.x * 64;
    int tid = threadIdx.x;
    int jj = tid & 63, part = tid >> 6;
    float s = 0.f;
    #pragma unroll
    for (int k = 0; k < 16; ++k) {
        int strip = part * 16 + k;
        s += Spart[((size_t)strip * 8 + b) * TN + j0 + jj];
    }
    ps[part][jj] = s;
    __syncthreads();
    if (tid < 64) {
        float tot = ps[0][tid] + ps[1][tid] + ps[2][tid] + ps[3][tid];
        int j = j0 + tid;
        if (j >= NN) {                 // identity column term (adj TR = I)
            int i = j - NN;
            tot += fmaxf(E1p[(size_t)b * TN + i] * E2p[(size_t)b * TN + j],
                         E1n[(size_t)b * TN + i] * E2n[(size_t)b * TN + j]);
        }
        rs[tid] = 1.0f / tot;
    }
    for (int e = tid; e < 4096; e += 256) {
        int jt = e >> 6, d = e & 63;
        tile[jt][d] = Wh[((size_t)b * TN + j0 + jt) * DD + d];
    }
    __syncthreads();
    for (int e = tid; e < 512; e += 256) {
        int d = e >> 3, jg = e & 7;
        union { unsigned short u[8]; short8 s8; } pk;
        #pragma unroll
        for (int k = 0; k < 8; ++k) {
            int jt = jg * 8 + k;
            pk.u[k] = f2bf(tile[jt][d] * rs[jt]);
        }
        *reinterpret_cast<short8*>(Wt + ((size_t)b * DD + d) * TN + j0 + jg * 8) = pk.s8;
    }
}

// K4 v3: each wave owns 32 i-rows (two 16-row groups acc0/acc1) so every
// B-fragment ds_read_b128 feeds TWO MFMAs. Block covers 128 i-rows; grid
// 1024 (4 blocks/CU). hpq layout unchanged (grp=it*8+w*2+gsel).
__global__ __launch_bounds__(256, 4) void k4_pv(
    const unsigned int* __restrict__ qmask32,
    const float* __restrict__ E1p, const float* __restrict__ E1n,
    const float* __restrict__ E2p, const float* __restrict__ E2n,
    const unsigned short* __restrict__ Wt,
    unsigned short* __restrict__ hpq) {
    __shared__ unsigned short wt_s[64 * 140];
    int bx = blockIdx.x;
    int b  = bx & 7;                 // XCD round-robin
    int js = (bx >> 3) & 3;
    int it = bx >> 5;                // i-tile index 0..31 (128 rows each)
    int i0 = it * 128;
    int half = (it >= 16);           // 0: i<2048 -> j in [0,2048); 1: [2048,4096)
    int tid = threadIdx.x;
    int w = tid >> 6, l = tid & 63;
    int m = l & 15, q = l >> 4;
    int irow0 = i0 + w * 32 + m;     // rows group 0
    int irow1 = irow0 + 16;          // rows group 1
    float e1p0 = E1p[(size_t)b * TN + irow0], e1n0 = E1n[(size_t)b * TN + irow0];
    float e1p1 = E1p[(size_t)b * TN + irow1], e1n1 = E1n[(size_t)b * TN + irow1];
    const float* e2pb = E2p + (size_t)b * TN;
    const float* e2nb = E2n + (size_t)b * TN;
    const unsigned short* wtb = Wt + (size_t)b * DD * TN;
    const unsigned int* mrow0 = qmask32 + (size_t)irow0 * 64;
    const unsigned int* mrow1 = qmask32 + (size_t)irow1 * 64;

    int r0 = tid >> 4, c0 = tid & 15;
    const int jbase = half * 2048 + js * 512;   // global j base
    const int jloc0 = js * 512;                 // local (in-half) bit base

    f32x4 acc0[4], acc1[4];
    #pragma unroll
    for (int dt = 0; dt < 4; ++dt) {
        acc0[dt] = (f32x4){0.f, 0.f, 0.f, 0.f};
        acc1[dt] = (f32x4){0.f, 0.f, 0.f, 0.f};
    }

    // prefetch tile jt=0 + masks jt=0
    short8 g[4];
    #pragma unroll
    for (int k = 0; k < 4; ++k)
        g[k] = *reinterpret_cast<const short8*>(
            wtb + (size_t)(r0 + 16 * k) * TN + jbase + c0 * 8);
    u32x4 m40 = *reinterpret_cast<const u32x4*>(mrow0 + (jloc0 >> 5));
    u32x4 m41 = *reinterpret_cast<const u32x4*>(mrow1 + (jloc0 >> 5));

    for (int jt = 0; jt < 4; ++jt) {
        int j0 = jbase + jt * 128;
        __syncthreads();                // prior reads done
        #pragma unroll
        for (int k = 0; k < 4; ++k)
            *reinterpret_cast<short8*>(&wt_s[(r0 + 16 * k) * 140 + c0 * 8]) = g[k];
        __syncthreads();                // tile visible
        u32x4 m40c = m40, m41c = m41;
        if (jt < 3) {                   // prefetch next tile DURING compute
            #pragma unroll
            for (int k = 0; k < 4; ++k)
                g[k] = *reinterpret_cast<const short8*>(
                    wtb + (size_t)(r0 + 16 * k) * TN + j0 + 128 + c0 * 8);
            m40 = *reinterpret_cast<const u32x4*>(
                mrow0 + ((jloc0 + (jt + 1) * 128) >> 5));
            m41 = *reinterpret_cast<const u32x4*>(
                mrow1 + ((jloc0 + (jt + 1) * 128) >> 5));
        }

        #pragma unroll
        for (int t = 0; t < 4; ++t) {
            int jb = j0 + t * 32 + q * 8;
            f32x4 p20 = *reinterpret_cast<const f32x4*>(e2pb + jb);
            f32x4 p21 = *reinterpret_cast<const f32x4*>(e2pb + jb + 4);
            f32x4 n20 = *reinterpret_cast<const f32x4*>(e2nb + jb);
            f32x4 n21 = *reinterpret_cast<const f32x4*>(e2nb + jb + 4);
            AF af0, af1;
            #pragma unroll
            for (int gsel = 0; gsel < 2; ++gsel) {
                float e1p_v = gsel ? e1p1 : e1p0;
                float e1n_v = gsel ? e1n1 : e1n0;
                unsigned int bytev = ((gsel ? m41c : m40c)[t] >> (q * 8)) & 0xFFu;
                f32x4 v0 = __builtin_elementwise_max(p20 * e1p_v, n20 * e1n_v);
                f32x4 v1 = __builtin_elementwise_max(p21 * e1p_v, n21 * e1n_v);
                union { f32x4 f; u32x4 u; } uv0, uv1;
                uv0.f = v0; uv1.f = v1;
                u32x4 mk0, mk1;
                #pragma unroll
                for (int c = 0; c < 4; ++c) {
                    mk0[c] = (unsigned int)((int)(bytev << (31 - c)) >> 31);
                    mk1[c] = (unsigned int)((int)(bytev << (27 - c)) >> 31);
                }
                uv0.u &= mk0; uv1.u &= mk1;
                __hip_bfloat162 hb0 = __float22bfloat162_rn(make_float2(uv0.f[0], uv0.f[1]));
                __hip_bfloat162 hb1 = __float22bfloat162_rn(make_float2(uv0.f[2], uv0.f[3]));
                __hip_bfloat162 hb2 = __float22bfloat162_rn(make_float2(uv1.f[0], uv1.f[1]));
                __hip_bfloat162 hb3 = __float22bfloat162_rn(make_float2(uv1.f[2], uv1.f[3]));
                AF& af = gsel ? af1 : af0;
                af.u[0] = *reinterpret_cast<unsigned int*>(&hb0);
                af.u[1] = *reinterpret_cast<unsigned int*>(&hb1);
                af.u[2] = *reinterpret_cast<unsigned int*>(&hb2);
                af.u[3] = *reinterpret_cast<unsigned int*>(&hb3);
            }
            #pragma unroll
            for (int dt = 0; dt < 4; ++dt) {
                short8 bf = *reinterpret_cast<const short8*>(
                    &wt_s[(dt * 16 + m) * 140 + t * 32 + q * 8]);   // 1 read, 2 MFMAs
                acc0[dt] = __builtin_amdgcn_mfma_f32_16x16x32_bf16(af0.s8, bf, acc0[dt], 0, 0, 0);
                acc1[dt] = __builtin_amdgcn_mfma_f32_16x16x32_bf16(af1.s8, bf, acc1[dt], 0, 0, 0);
            }
        }
    }

    // Diagonal identity term + epilogue per 16-row group.
    #pragma unroll
    for (int gsel = 0; gsel < 2; ++gsel) {
        f32x4* acc = gsel ? acc1 : acc0;
        int gbase = i0 + w * 32 + gsel * 16 + q * 4;
        if (half == 0 && js == 0) {
            #pragma unroll
            for (int r = 0; r < 4; ++r) {
                int gg = gbase + r;
                float ed = fmaxf(E1p[(size_t)b * TN + gg] * e2pb[gg + NN],
                                 E1n[(size_t)b * TN + gg] * e2nb[gg + NN]);
                #pragma unroll
                for (int dt = 0; dt < 4; ++dt) {
                    int d = dt * 16 + m;
                    acc[dt][r] += ed * bf2f(wtb[(size_t)d * TN + gg + NN]);
                }
            }
        }
        // lane-native bf16 pack; row-group index grp keeps k5 layout intact
        union { unsigned int u[8]; u32x4 v[2]; } pk;
        #pragma unroll
        for (int dt = 0; dt < 4; ++dt) {
            __hip_bfloat162 p0 = __float22bfloat162_rn(make_float2(acc[dt][0], acc[dt][1]));
            __hip_bfloat162 p1 = __float22bfloat162_rn(make_float2(acc[dt][2], acc[dt][3]));
            pk.u[dt * 2 + 0] = *reinterpret_cast<unsigned int*>(&p0);
            pk.u[dt * 2 + 1] = *reinterpret_cast<unsigned int*>(&p1);
        }
        int grp = it * 8 + w * 2 + gsel;           // absolute 16-row group 0..255
        unsigned short* hp = hpq +
            ((((size_t)js * 8 + b) * 256 + grp) * 64 + l) * 16;
        *reinterpret_cast<u32x4*>(hp)     = pk.v[0];
        *reinterpret_cast<u32x4*>(hp + 8) = pk.v[1];
    }
}

// K5: block = (b,it), wave geometry MATCHES k4's writes -> fully coalesced
// u32x4 reads. js-sum in f32, ELU, LDS transpose [64][68], vector f32
// stores with concat remap. 24 MB total traffic.
__global__ __launch_bounds__(256) void k5_epi(const unsigned short* __restrict__ hpq,
                                              float* __restrict__ out) {
    __shared__ float tile[64][68];
    int bx = blockIdx.x;                 // 0..511
    int b  = bx & 7;
    int it = bx >> 3;                    // 0..63
    int tid = threadIdx.x;
    int w = tid >> 6, l = tid & 63;
    int m = l & 15, q = l >> 4;
    const size_t JSTR = (size_t)8 * 64 * 4 * 64 * 16;   // ushorts per js slab
    size_t base = ((((size_t)b * 64 + it) * 4 + w) * 64 + l) * 16;
    float sum[16];
    #pragma unroll
    for (int k = 0; k < 16; ++k) sum[k] = 0.f;
    #pragma unroll
    for (int js = 0; js < 4; ++js) {
        const u32x4* p = reinterpret_cast<const u32x4*>(hpq + js * JSTR + base);
        u32x4 v0 = p[0], v1 = p[1];
        unsigned int uu[8];
        *reinterpret_cast<u32x4*>(&uu[0]) = v0;
        *reinterpret_cast<u32x4*>(&uu[4]) = v1;
        #pragma unroll
        for (int k = 0; k < 16; ++k) {
            int word = (k >> 2) * 2 + ((k >> 1) & 1);
            int hi = k & 1;
            sum[k] += bf2f((unsigned short)((uu[word] >> (hi * 16)) & 0xFFFFu));
        }
    }
    // ELU then scatter into LDS transpose tile: row=w*16+q*4+r, col=dt*16+m
    #pragma unroll
    for (int dt = 0; dt < 4; ++dt) {
        #pragma unroll
        for (int r = 0; r < 4; ++r) {
            float v = sum[dt * 4 + r];
            v = (v > 0.f) ? v : expm1f(v);
            tile[w * 16 + q * 4 + r][dt * 16 + m] = v;
        }
    }
    __syncthreads();
    int rl = tid >> 2, c0 = (tid & 3) * 16;
    int gg = it * 64 + rl;
    int half = (it >= 32);
    int n = gg - half * NN;
    float* orow = out + ((size_t)b * NN + n) * 128 + half * 64 + c0;
    #pragma unroll
    for (int c = 0; c < 4; ++c)
        *reinterpret_cast<f32x4*>(orow + c * 4) =
            *reinterpret_cast<const f32x4*>(&tile[rl][c0 + c * 4]);
}

extern "C" void kernel_launch(void* const* d_in, const int* in_sizes, int n_in,
                              void* d_out, int out_size, void* d_ws, size_t ws_size,
                              hipStream_t stream) {
    const float* h   = (const float*)d_in[0];
    const float* ht  = (const float*)d_in[1];
    const float* W   = (const float*)d_in[2];
    const float* a1  = (const float*)d_in[3];
    const float* a2  = (const float*)d_in[4];
    const float* adj = (const float*)d_in[5];
    float* out = (float*)d_out;

    char* ws = (char*)d_ws;
    float* Wh          = (float*)(ws);                       // 8 MB
    float* Spart       = (float*)(ws + (8 << 20));           // 8 MB (64 strips)
    unsigned short* Wt = (unsigned short*)(ws + (16 << 20)); // 4 MB
    float* E1p         = (float*)(ws + (20 << 20));
    float* E1n         = (float*)(ws + (20 << 20) + (128 << 10));
    float* E2p         = (float*)(ws + (20 << 20) + (256 << 10));
    float* E2n         = (float*)(ws + (20 << 20) + (384 << 10));
    unsigned long long* qmask = (unsigned long long*)(ws + (20 << 20) + (512 << 10)); // 1 MB
    float* E1i         = (float*)(ws + (20 << 20) + (512 << 10) + (2 << 20)); // 256 KB
    const unsigned int* qmask32 = (const unsigned int*)qmask;
    // 4 bf16 partial slabs (4 MB each, lane-native layout) overlay Wh+Spart
    unsigned short* hpq = (unsigned short*)ws;               // 16 MB total

    k1_wh<<<dim3(BB * TN / 32), dim3(256), 0, stream>>>(h, ht, W, a1, a2, Wh,
                                                        E1p, E1n, E2p, E2n, E1i);
    k2_mask_stats<<<dim3(8, 64, 2), dim3(256), 0, stream>>>(adj, E1i, E2p, E2n,
                                                            qmask, Spart);
    k3_whn<<<dim3(64, 8), dim3(256), 0, stream>>>(Wh, Spart, E1p, E1n, E2p, E2n, Wt);
    k4_pv<<<dim3(1024), dim3(256), 0, stream>>>(qmask32, E1p, E1n, E2p, E2n, Wt,
                                                hpq);
    k5_epi<<<dim3(512), dim3(256), 0, stream>>>(hpq, out);
}